// Round 3
// baseline (202.705 us; speedup 1.0000x reference)
//
#include <hip/hip_runtime.h>

#define EPSV 1e-5f

typedef __bf16 bf16_t;
typedef __bf16 bf16x8 __attribute__((ext_vector_type(8)));
typedef float f32x4 __attribute__((ext_vector_type(4)));

__device__ inline bf16x8 bzero8() {
  bf16x8 z;
#pragma unroll
  for (int i = 0; i < 8; i++) z[i] = (bf16_t)0.f;
  return z;
}

__device__ inline f32x4 mfma16(bf16x8 a, bf16x8 b, f32x4 c) {
  return __builtin_amdgcn_mfma_f32_16x16x32_bf16(a, b, c, 0, 0, 0);
}

// ---------------- weight prep: fp32 -> bf16, padded + reordered ----------------
// w1b [160][608]        (row=oc, k=ic)               oc>=152 zero
// w2b [384][1376]       (row=oc, k=tap*152+ic)       pads zero
// wdb [192][1376]       (row=o,  k=tap*152+ic)       pads zero   (t-major, ic=g*8+cg)
// w3b [640][160]        (row=oc, k=ic)               k>=152 / oc>=608 zero
#define W1E (160 * 608)
#define W2E (384 * 1376)
#define WDE (192 * 1376)
#define W3E (640 * 160)

__global__ __launch_bounds__(256) void prep_weights(
    const float* __restrict__ w1, const float* __restrict__ w2,
    const float* __restrict__ wd, const float* __restrict__ w3,
    bf16_t* __restrict__ w1b, bf16_t* __restrict__ w2b,
    bf16_t* __restrict__ wdb, bf16_t* __restrict__ w3b) {
  int i = blockIdx.x * 256 + threadIdx.x;
  float v = 0.f;
  if (i < W1E) {
    int oc = i / 608, ic = i % 608;
    if (oc < 152) v = w1[oc * 608 + ic];
    w1b[i] = (bf16_t)v;
  } else if (i < W1E + W2E) {
    int j = i - W1E;
    int oc = j / 1376, k = j % 1376;
    if (oc < 342 && k < 1368) {
      int t = k / 152, ic = k % 152;
      v = w2[(oc * 152 + ic) * 9 + t];
    }
    w2b[j] = (bf16_t)v;
  } else if (i < W1E + W2E + WDE) {
    int j = i - W1E - W2E;
    int o = j / 1376, k = j % 1376;
    if (o < 152 && k < 1368) {
      int t = k / 152, ic = k % 152;
      v = wd[(o * 152 + ic) * 9 + t];
    }
    wdb[j] = (bf16_t)v;
  } else if (i < W1E + W2E + WDE + W3E) {
    int j = i - W1E - W2E - WDE;
    int oc = j / 160, ic = j % 160;
    if (oc < 608 && ic < 152) v = w3[oc * 152 + ic];
    w3b[j] = (bf16_t)v;
  }
}

// bnc layout: [0,152) inv1, [152,304) beta1, [304,456) inv2, [456,608) beta2,
//             [608,1216) inv3, [1216,1824) beta3
__global__ void prep_bn(const float* g1, const float* b1, const float* m1, const float* v1,
                        const float* g2, const float* b2, const float* m2, const float* v2,
                        const float* g3, const float* b3, const float* m3, const float* v3,
                        float* __restrict__ bnc) {
  int i = threadIdx.x;
  if (i < 152) {
    float inv = g1[i] / sqrtf(v1[i] + EPSV);
    bnc[i] = inv;
    bnc[152 + i] = b1[i] - m1[i] * inv;
    float inv2 = g2[i] / sqrtf(v2[i] + EPSV);
    bnc[304 + i] = inv2;
    bnc[456 + i] = b2[i] - m2[i] * inv2;
  }
  if (i < 608) {
    float inv3 = g3[i] / sqrtf(v3[i] + EPSV);
    bnc[608 + i] = inv3;
    bnc[1216 + i] = b3[i] - m3[i] * inv3;
  }
}

// ---------------- S1: conv1 1x1 (K=608,N=152) + relu + bn1 -> out1 NHWC bf16 ----------------
// block 256 thr, 32 px; LDS-staged NCHW->NHWC bf16 tile [32][616]; 4 waves = 2M x 2N
__global__ __launch_bounds__(256) void s1_conv1(const float* __restrict__ x,
                                                const bf16_t* __restrict__ w1b,
                                                const float* __restrict__ bnc,
                                                bf16_t* __restrict__ out1) {
  __shared__ bf16_t t1[32 * 616];  // 38.5 KB
  int tid = threadIdx.x;
  int px0 = blockIdx.x * 32;
  int b = px0 >> 12, sp0 = px0 & 4095;
  // stage: 608 ch x 8 float4 chunks (32 px), fully-coalesced global reads
  for (int task = tid; task < 608 * 8; task += 256) {
    int c = task >> 3, i4 = task & 7;
    f32x4 v = *(const f32x4*)(x + (((size_t)(b * 608 + c)) << 12) + sp0 + i4 * 4);
#pragma unroll
    for (int i = 0; i < 4; i++) t1[(i4 * 4 + i) * 616 + c] = (bf16_t)v[i];
  }
  __syncthreads();
  int wid = tid >> 6, lane = tid & 63, q = lane >> 4, lr = lane & 15;
  int mw = wid & 1, nw = wid >> 1;  // 2M x 2N
  f32x4 acc[5];
#pragma unroll
  for (int n = 0; n < 5; n++) acc[n] = (f32x4){0.f, 0.f, 0.f, 0.f};
  for (int kk = 0; kk < 19; kk++) {
    int k0 = kk * 32 + q * 8;
    bf16x8 a = *(const bf16x8*)(t1 + (mw * 16 + lr) * 616 + k0);
#pragma unroll
    for (int n = 0; n < 5; n++) {
      bf16x8 bf = *(const bf16x8*)(w1b + (nw * 80 + n * 16 + lr) * 608 + k0);
      acc[n] = mfma16(a, bf, acc[n]);
    }
  }
#pragma unroll
  for (int n = 0; n < 5; n++) {
    int oc = nw * 80 + n * 16 + lr;
    if (oc < 152) {
      float inv = bnc[oc], beta = bnc[152 + oc];
#pragma unroll
      for (int i = 0; i < 4; i++) {
        int p = px0 + mw * 16 + q * 4 + i;
        float v = fmaxf(acc[n][i], 0.f) * inv + beta;
        out1[(size_t)p * 152 + oc] = (bf16_t)v;
      }
    }
  }
}

// ---------------- S2: offset conv 3x3 (K=1368->1376, N=342->384) -> offs fp32 [pix][t*38+g*2+c] ----------------
// block 512 thr, half image row (32 px); compact halo tile 3x34x152 in LDS;
// 8 waves each own 48 distinct output cols x all 32 px (B read once per block)
__global__ __launch_bounds__(512) void s2_offs(const bf16_t* __restrict__ out1,
                                               const bf16_t* __restrict__ w2b,
                                               float* __restrict__ offs) {
  __shared__ bf16_t t2[102 * 152];  // 31 KB
  int tid = threadIdx.x;
  int xh = blockIdx.x & 1, y = (blockIdx.x >> 1) & 63, b = blockIdx.x >> 7;
  const bf16_t* ob = out1 + (((size_t)b) << 12) * 152;
  int x0 = xh * 32 - 1;
  // stage 3 rows (y-1..y+1) x 34 px (x0..x0+33) x 152 ch, OOB -> 0
  for (int task = tid; task < 3 * 34 * 19; task += 512) {
    int j = task / 646, r = task % 646;
    int xi = r / 19, cb = r % 19;
    int yy = y + j - 1, xx = x0 + xi;
    bf16x8 v = bzero8();
    if (yy >= 0 && yy < 64 && xx >= 0 && xx < 64)
      v = *(const bf16x8*)(ob + (size_t)(yy * 64 + xx) * 152 + cb * 8);
    *(bf16x8*)(t2 + (j * 34 + xi) * 152 + cb * 8) = v;
  }
  __syncthreads();
  int wid = tid >> 6, lane = tid & 63, q = lane >> 4, lr = lane & 15;
  f32x4 acc[2][3];
#pragma unroll
  for (int m = 0; m < 2; m++)
#pragma unroll
    for (int n = 0; n < 3; n++) acc[m][n] = (f32x4){0.f, 0.f, 0.f, 0.f};
  for (int kk = 0; kk < 43; kk++) {
    int k0 = kk * 32 + q * 8;
    bf16x8 a[2];
    if (k0 < 1368) {
      int t = k0 / 152, c0 = k0 - t * 152;
      int dy = t / 3, dxp1 = t - dy * 3;  // 0..2
      int base = (dy * 34 + lr + dxp1) * 152 + c0;
#pragma unroll
      for (int m = 0; m < 2; m++) a[m] = *(const bf16x8*)(t2 + base + m * 16 * 152);
    } else {
      a[0] = bzero8();
      a[1] = bzero8();
    }
#pragma unroll
    for (int n = 0; n < 3; n++) {
      bf16x8 bf = *(const bf16x8*)(w2b + (size_t)(wid * 48 + n * 16 + lr) * 1376 + k0);
#pragma unroll
      for (int m = 0; m < 2; m++) acc[m][n] = mfma16(a[m], bf, acc[m][n]);
    }
  }
#pragma unroll
  for (int n = 0; n < 3; n++) {
    int col = wid * 48 + n * 16 + lr;
    if (col < 342) {
      int g = col / 18, rem = col % 18;
      int t = rem >> 1, c = rem & 1;
      int pos = t * 38 + g * 2 + c;
#pragma unroll
      for (int m = 0; m < 2; m++)
#pragma unroll
        for (int i = 0; i < 4; i++) {
          int p = (b << 12) + y * 64 + xh * 32 + m * 16 + q * 4 + i;
          offs[(size_t)p * 344 + pos] = acc[m][n][i];
        }
    }
  }
}

// ---------------- S3: deform sample + GEMM (K=1368 t-major, N=152->192) + relu + bn2 -> a2 NHWC bf16 ----------------
// sampling: 171 active threads x 16 rows, [r][t][g] order -> coalesced offsets,
// near-contiguous gathers, contiguous ds_write_b128
__global__ __launch_bounds__(256, 3) void s3_dconv(const bf16_t* __restrict__ out1,
                                                   const float* __restrict__ offs,
                                                   const bf16_t* __restrict__ wdb,
                                                   const float* __restrict__ bnc,
                                                   bf16_t* __restrict__ a2) {
  __shared__ bf16_t alds[16 * 1368];  // 43.8 KB
  int tid = threadIdx.x;
  int row0 = blockIdx.x * 16;
  if (tid < 171) {
    int t = tid / 19, g = tid - t * 19;
    int ky = t / 3, kx = t - ky * 3;
    int bb = row0 >> 12;
    const bf16_t* base = out1 + (((size_t)bb << 12) * 152) + g * 8;
    const float* op0 = offs + (size_t)row0 * 344 + t * 38 + g * 2;
    bf16_t* ldst = alds + t * 152 + g * 8;
#pragma unroll
    for (int r = 0; r < 16; r++) {
      int p = row0 + r;
      int y = (p >> 6) & 63, xc = p & 63;
      float2 ov = *(const float2*)(op0 + (size_t)r * 344);
      float ys = (float)(y - 1 + ky) + ov.x;
      float xs = (float)(xc - 1 + kx) + ov.y;
      float y0f = floorf(ys), x0f = floorf(xs);
      float wy = ys - y0f, wx = xs - x0f;
      int y0 = (int)y0f, x0 = (int)x0f;
      float fa[8];
#pragma unroll
      for (int i = 0; i < 8; i++) fa[i] = 0.f;
      float wws[4] = {(1.f - wy) * (1.f - wx), (1.f - wy) * wx,
                      wy * (1.f - wx), wy * wx};
      int yy[4] = {y0, y0, y0 + 1, y0 + 1};
      int xx[4] = {x0, x0 + 1, x0, x0 + 1};
#pragma unroll
      for (int cn = 0; cn < 4; cn++) {
        if (yy[cn] >= 0 && yy[cn] < 64 && xx[cn] >= 0 && xx[cn] < 64) {
          bf16x8 v = *(const bf16x8*)(base + (size_t)(yy[cn] * 64 + xx[cn]) * 152);
#pragma unroll
          for (int i = 0; i < 8; i++) fa[i] += wws[cn] * (float)v[i];
        }
      }
      bf16x8 o;
#pragma unroll
      for (int i = 0; i < 8; i++) o[i] = (bf16_t)fa[i];
      *(bf16x8*)(ldst + r * 1368) = o;
    }
  }
  __syncthreads();
  // GEMM phase: 4 waves, each 3 n-frags (N padded to 192), same 16 rows
  int wid = tid >> 6, lane = tid & 63, q = lane >> 4, lr = lane & 15;
  int nb = wid * 3;
  f32x4 acc[3];
#pragma unroll
  for (int n = 0; n < 3; n++) acc[n] = (f32x4){0.f, 0.f, 0.f, 0.f};
  for (int kk = 0; kk < 43; kk++) {
    int k0 = kk * 32 + q * 8;
    bf16x8 a = (k0 < 1368) ? *(const bf16x8*)(alds + lr * 1368 + k0) : bzero8();
#pragma unroll
    for (int n = 0; n < 3; n++) {
      bf16x8 bf = *(const bf16x8*)(wdb + (size_t)((nb + n) * 16 + lr) * 1376 + k0);
      acc[n] = mfma16(a, bf, acc[n]);
    }
  }
#pragma unroll
  for (int n = 0; n < 3; n++) {
    int oc = (nb + n) * 16 + lr;
    if (oc < 152) {
      float inv = bnc[304 + oc], beta = bnc[456 + oc];
#pragma unroll
      for (int i = 0; i < 4; i++) {
        int p = row0 + q * 4 + i;
        float v = fmaxf(acc[n][i], 0.f) * inv + beta;
        a2[(size_t)p * 152 + oc] = (bf16_t)v;
      }
    }
  }
}

// ---------------- S4: conv3 1x1 (K=152->160, N=608->640) + bn3 + residual + relu -> out NCHW fp32 ----------------
// block 256 thr, 16 px; 4 waves split N (10 frags each); float4 residual+store
__global__ __launch_bounds__(256) void s4_conv3(const bf16_t* __restrict__ a2,
                                                const bf16_t* __restrict__ w3b,
                                                const float* __restrict__ bnc,
                                                const float* __restrict__ x,
                                                float* __restrict__ out) {
  int tid = threadIdx.x;
  int wid = tid >> 6, lane = tid & 63, q = lane >> 4, lr = lane & 15;
  int p0 = blockIdx.x * 16;
  int b = p0 >> 12, sp0 = p0 & 4095;
  f32x4 acc[10];
#pragma unroll
  for (int n = 0; n < 10; n++) acc[n] = (f32x4){0.f, 0.f, 0.f, 0.f};
  for (int kk = 0; kk < 5; kk++) {
    int k0 = kk * 32 + q * 8;
    bf16x8 a = (k0 < 152) ? *(const bf16x8*)(a2 + (size_t)(p0 + lr) * 152 + k0) : bzero8();
#pragma unroll
    for (int n = 0; n < 10; n++) {
      bf16x8 bf = *(const bf16x8*)(w3b + (size_t)(wid * 160 + n * 16 + lr) * 160 + k0);
      acc[n] = mfma16(a, bf, acc[n]);
    }
  }
#pragma unroll
  for (int n = 0; n < 10; n++) {
    int oc = wid * 160 + n * 16 + lr;
    if (oc < 608) {
      float inv = bnc[608 + oc], beta = bnc[1216 + oc];
      size_t gi = (((size_t)(b * 608 + oc)) << 12) + sp0 + q * 4;
      f32x4 xr = *(const f32x4*)(x + gi);
      f32x4 o;
#pragma unroll
      for (int i = 0; i < 4; i++) o[i] = fmaxf(acc[n][i] * inv + beta + xr[i], 0.f);
      *(f32x4*)(out + gi) = o;
    }
  }
}

extern "C" void kernel_launch(void* const* d_in, const int* in_sizes, int n_in,
                              void* d_out, int out_size, void* d_ws, size_t ws_size,
                              hipStream_t stream) {
  const float* x = (const float*)d_in[0];
  const float* w1 = (const float*)d_in[1];
  const float* w2 = (const float*)d_in[2];
  const float* wd = (const float*)d_in[3];
  const float* w3 = (const float*)d_in[4];
  const float* g1 = (const float*)d_in[5];
  const float* b1 = (const float*)d_in[6];
  const float* m1 = (const float*)d_in[7];
  const float* v1 = (const float*)d_in[8];
  const float* g2 = (const float*)d_in[9];
  const float* b2 = (const float*)d_in[10];
  const float* m2 = (const float*)d_in[11];
  const float* v2 = (const float*)d_in[12];
  const float* g3 = (const float*)d_in[13];
  const float* b3 = (const float*)d_in[14];
  const float* m3 = (const float*)d_in[15];
  const float* v3 = (const float*)d_in[16];

  char* ws = (char*)d_ws;
  bf16_t* w1b = (bf16_t*)(ws + 0);          // 160*608*2  = 194560
  bf16_t* w2b = (bf16_t*)(ws + 194560);     // 384*1376*2 = 1056768
  bf16_t* wdb = (bf16_t*)(ws + 1251328);    // 192*1376*2 = 528384
  bf16_t* w3b = (bf16_t*)(ws + 1779712);    // 640*160*2  = 204800
  float* bnc = (float*)(ws + 1984512);      // 1824*4     = 7296
  bf16_t* out1 = (bf16_t*)(ws + 1991808);   // 16384*152*2 = 4980736
  float* offs = (float*)(ws + 6972544);     // 16384*344*4 = 22544384
  bf16_t* a2 = (bf16_t*)(ws + 29516928);    // 16384*152*2 = 4980736  end 34497664
  float* out = (float*)d_out;

  prep_weights<<<3876, 256, 0, stream>>>(w1, w2, wd, w3, w1b, w2b, wdb, w3b);
  prep_bn<<<1, 640, 0, stream>>>(g1, b1, m1, v1, g2, b2, m2, v2, g3, b3, m3, v3, bnc);
  s1_conv1<<<512, 256, 0, stream>>>(x, w1b, bnc, out1);
  s2_offs<<<512, 512, 0, stream>>>(out1, w2b, offs);
  s3_dconv<<<1024, 256, 0, stream>>>(out1, offs, wdb, bnc, a2);
  s4_conv3<<<1024, 256, 0, stream>>>(a2, w3b, bnc, x, out);
}

// Round 4
// 176.663 us; speedup vs baseline: 1.1474x; 1.1474x over previous
//
#include <hip/hip_runtime.h>

#define EPSV 1e-5f

typedef __bf16 bf16_t;
typedef __bf16 bf16x8 __attribute__((ext_vector_type(8)));
typedef float f32x4 __attribute__((ext_vector_type(4)));

__device__ inline bf16x8 bzero8() {
  bf16x8 z;
#pragma unroll
  for (int i = 0; i < 8; i++) z[i] = (bf16_t)0.f;
  return z;
}

__device__ inline f32x4 mfma16(bf16x8 a, bf16x8 b, f32x4 c) {
  return __builtin_amdgcn_mfma_f32_16x16x32_bf16(a, b, c, 0, 0, 0);
}

// ---------------- weight prep: fp32 -> bf16, padded + reordered ----------------
// w1b [160][608]        (row=oc, k=ic)               oc>=152 zero
// w2b [384][1376]       (row=oc, k=tap*152+ic)       pads zero
// wdb [192][1440]       (row=o,  k=tap*160+ic)       pads zero (per-tap k-slice padded to 160)
// w3b [640][160]        (row=oc, k=ic)               k>=152 / oc>=608 zero
#define W1E (160 * 608)
#define W2E (384 * 1376)
#define WDE (192 * 1440)
#define W3E (640 * 160)

__global__ __launch_bounds__(256) void prep_weights(
    const float* __restrict__ w1, const float* __restrict__ w2,
    const float* __restrict__ wd, const float* __restrict__ w3,
    bf16_t* __restrict__ w1b, bf16_t* __restrict__ w2b,
    bf16_t* __restrict__ wdb, bf16_t* __restrict__ w3b) {
  int i = blockIdx.x * 256 + threadIdx.x;
  float v = 0.f;
  if (i < W1E) {
    int oc = i / 608, ic = i % 608;
    if (oc < 152) v = w1[oc * 608 + ic];
    w1b[i] = (bf16_t)v;
  } else if (i < W1E + W2E) {
    int j = i - W1E;
    int oc = j / 1376, k = j % 1376;
    if (oc < 342 && k < 1368) {
      int t = k / 152, ic = k % 152;
      v = w2[(oc * 152 + ic) * 9 + t];
    }
    w2b[j] = (bf16_t)v;
  } else if (i < W1E + W2E + WDE) {
    int j = i - W1E - W2E;
    int o = j / 1440, k = j % 1440;
    int t = k / 160, ic = k % 160;
    if (o < 152 && ic < 152) v = wd[(o * 152 + ic) * 9 + t];
    wdb[j] = (bf16_t)v;
  } else if (i < W1E + W2E + WDE + W3E) {
    int j = i - W1E - W2E - WDE;
    int oc = j / 160, ic = j % 160;
    if (oc < 608 && ic < 152) v = w3[oc * 152 + ic];
    w3b[j] = (bf16_t)v;
  }
}

// bnc layout: [0,152) inv1, [152,304) beta1, [304,456) inv2, [456,608) beta2,
//             [608,1216) inv3, [1216,1824) beta3
__global__ void prep_bn(const float* g1, const float* b1, const float* m1, const float* v1,
                        const float* g2, const float* b2, const float* m2, const float* v2,
                        const float* g3, const float* b3, const float* m3, const float* v3,
                        float* __restrict__ bnc) {
  int i = threadIdx.x;
  if (i < 152) {
    float inv = g1[i] / sqrtf(v1[i] + EPSV);
    bnc[i] = inv;
    bnc[152 + i] = b1[i] - m1[i] * inv;
    float inv2 = g2[i] / sqrtf(v2[i] + EPSV);
    bnc[304 + i] = inv2;
    bnc[456 + i] = b2[i] - m2[i] * inv2;
  }
  if (i < 608) {
    float inv3 = g3[i] / sqrtf(v3[i] + EPSV);
    bnc[608 + i] = inv3;
    bnc[1216 + i] = b3[i] - m3[i] * inv3;
  }
}

// ---------------- S1: conv1 1x1 (K=608,N=152) + relu + bn1 -> out1 NHWC bf16 ----------------
__global__ __launch_bounds__(256) void s1_conv1(const float* __restrict__ x,
                                                const bf16_t* __restrict__ w1b,
                                                const float* __restrict__ bnc,
                                                bf16_t* __restrict__ out1) {
  __shared__ bf16_t t1[32 * 616];  // 38.5 KB
  int tid = threadIdx.x;
  int px0 = blockIdx.x * 32;
  int b = px0 >> 12, sp0 = px0 & 4095;
  for (int task = tid; task < 608 * 8; task += 256) {
    int c = task >> 3, i4 = task & 7;
    f32x4 v = *(const f32x4*)(x + (((size_t)(b * 608 + c)) << 12) + sp0 + i4 * 4);
#pragma unroll
    for (int i = 0; i < 4; i++) t1[(i4 * 4 + i) * 616 + c] = (bf16_t)v[i];
  }
  __syncthreads();
  int wid = tid >> 6, lane = tid & 63, q = lane >> 4, lr = lane & 15;
  int mw = wid & 1, nw = wid >> 1;  // 2M x 2N
  f32x4 acc[5];
#pragma unroll
  for (int n = 0; n < 5; n++) acc[n] = (f32x4){0.f, 0.f, 0.f, 0.f};
  for (int kk = 0; kk < 19; kk++) {
    int k0 = kk * 32 + q * 8;
    bf16x8 a = *(const bf16x8*)(t1 + (mw * 16 + lr) * 616 + k0);
#pragma unroll
    for (int n = 0; n < 5; n++) {
      bf16x8 bf = *(const bf16x8*)(w1b + (nw * 80 + n * 16 + lr) * 608 + k0);
      acc[n] = mfma16(a, bf, acc[n]);
    }
  }
#pragma unroll
  for (int n = 0; n < 5; n++) {
    int oc = nw * 80 + n * 16 + lr;
    if (oc < 152) {
      float inv = bnc[oc], beta = bnc[152 + oc];
#pragma unroll
      for (int i = 0; i < 4; i++) {
        int p = px0 + mw * 16 + q * 4 + i;
        float v = fmaxf(acc[n][i], 0.f) * inv + beta;
        out1[(size_t)p * 152 + oc] = (bf16_t)v;
      }
    }
  }
}

// ---------------- S2: offset conv 3x3 (K=1368->1376, N=342->384) -> offs fp32 [pix][t*38+g*2+c] ----------------
__global__ __launch_bounds__(512) void s2_offs(const bf16_t* __restrict__ out1,
                                               const bf16_t* __restrict__ w2b,
                                               float* __restrict__ offs) {
  __shared__ bf16_t t2[102 * 152];  // 31 KB
  int tid = threadIdx.x;
  int xh = blockIdx.x & 1, y = (blockIdx.x >> 1) & 63, b = blockIdx.x >> 7;
  const bf16_t* ob = out1 + (((size_t)b) << 12) * 152;
  int x0 = xh * 32 - 1;
  for (int task = tid; task < 3 * 34 * 19; task += 512) {
    int j = task / 646, r = task % 646;
    int xi = r / 19, cb = r % 19;
    int yy = y + j - 1, xx = x0 + xi;
    bf16x8 v = bzero8();
    if (yy >= 0 && yy < 64 && xx >= 0 && xx < 64)
      v = *(const bf16x8*)(ob + (size_t)(yy * 64 + xx) * 152 + cb * 8);
    *(bf16x8*)(t2 + (j * 34 + xi) * 152 + cb * 8) = v;
  }
  __syncthreads();
  int wid = tid >> 6, lane = tid & 63, q = lane >> 4, lr = lane & 15;
  f32x4 acc[2][3];
#pragma unroll
  for (int m = 0; m < 2; m++)
#pragma unroll
    for (int n = 0; n < 3; n++) acc[m][n] = (f32x4){0.f, 0.f, 0.f, 0.f};
  for (int kk = 0; kk < 43; kk++) {
    int k0 = kk * 32 + q * 8;
    bf16x8 a[2];
    if (k0 < 1368) {
      int t = k0 / 152, c0 = k0 - t * 152;
      int dy = t / 3, dxp1 = t - dy * 3;
      int base = (dy * 34 + lr + dxp1) * 152 + c0;
#pragma unroll
      for (int m = 0; m < 2; m++) a[m] = *(const bf16x8*)(t2 + base + m * 16 * 152);
    } else {
      a[0] = bzero8();
      a[1] = bzero8();
    }
#pragma unroll
    for (int n = 0; n < 3; n++) {
      bf16x8 bf = *(const bf16x8*)(w2b + (size_t)(wid * 48 + n * 16 + lr) * 1376 + k0);
#pragma unroll
      for (int m = 0; m < 2; m++) acc[m][n] = mfma16(a[m], bf, acc[m][n]);
    }
  }
#pragma unroll
  for (int n = 0; n < 3; n++) {
    int col = wid * 48 + n * 16 + lr;
    if (col < 342) {
      int g = col / 18, rem = col % 18;
      int t = rem >> 1, c = rem & 1;
      int pos = t * 38 + g * 2 + c;
#pragma unroll
      for (int m = 0; m < 2; m++)
#pragma unroll
        for (int i = 0; i < 4; i++) {
          int p = (b << 12) + y * 64 + xh * 32 + m * 16 + q * 4 + i;
          offs[(size_t)p * 344 + pos] = acc[m][n][i];
        }
    }
  }
}

// ---------------- S3: deform sample + GEMM, tap-pipelined ----------------
// LDS: offsets [16][344] f32 (22 KB) + A double-buffer [2][16][168] bf16 (10.5 KB) = 32 KB
// for t in 0..8: sample tap t+1 into buf^1 (304 tasks, all 256 thr) || GEMM tap t from buf
__global__ __launch_bounds__(256, 4) void s3_dconv(const bf16_t* __restrict__ out1,
                                                   const float* __restrict__ offs,
                                                   const bf16_t* __restrict__ wdb,
                                                   const float* __restrict__ bnc,
                                                   bf16_t* __restrict__ a2) {
  __shared__ float olds[16 * 344];       // 22016 B
  __shared__ bf16_t abuf[2 * 16 * 168];  // 10752 B
  int tid = threadIdx.x;
  int row0 = blockIdx.x * 16;
  int bb = row0 >> 12;
  const bf16_t* obase = out1 + (((size_t)bb << 12) * 152);
  // zero the k-pad columns (152..167) of both buffers
  if (tid < 64) {
    int cur = tid >> 5, r = (tid >> 1) & 15, ch = tid & 1;
    *(bf16x8*)(abuf + cur * 2688 + r * 168 + 152 + ch * 8) = bzero8();
  }
  // stage all offsets for these 16 px: 16 x 86 f32x4, coalesced
  for (int task = tid; task < 16 * 86; task += 256) {
    int r = task / 86, cc = task - r * 86;
    *(f32x4*)(olds + r * 344 + cc * 4) =
        *(const f32x4*)(offs + (size_t)(row0 + r) * 344 + cc * 4);
  }
  __syncthreads();

  int wid = tid >> 6, lane = tid & 63, q = lane >> 4, lr = lane & 15;
  f32x4 acc[3];
#pragma unroll
  for (int n = 0; n < 3; n++) acc[n] = (f32x4){0.f, 0.f, 0.f, 0.f};

#define SAMPLE_TAP(T, CUR)                                                        \
  {                                                                               \
    int t_ = (T);                                                                 \
    int ky = t_ / 3, kx = t_ - ky * 3;                                            \
    for (int task = tid; task < 304; task += 256) {                               \
      int r = task / 19, g = task - r * 19;                                       \
      int p = row0 + r;                                                           \
      int y = (p >> 6) & 63, xc = p & 63;                                         \
      float2 ov = *(const float2*)(olds + r * 344 + t_ * 38 + g * 2);             \
      float ys = (float)(y - 1 + ky) + ov.x;                                      \
      float xs = (float)(xc - 1 + kx) + ov.y;                                     \
      float y0f = floorf(ys), x0f = floorf(xs);                                   \
      float wy = ys - y0f, wx = xs - x0f;                                         \
      int y0 = (int)y0f, x0 = (int)x0f;                                           \
      int y1 = y0 + 1, x1 = x0 + 1;                                               \
      int y0c = min(max(y0, 0), 63), x0c = min(max(x0, 0), 63);                   \
      int y1c = min(max(y1, 0), 63), x1c = min(max(x1, 0), 63);                   \
      float vy0 = (y0 == y0c) ? 1.f : 0.f;                                        \
      float vy1 = (y1 == y1c) ? 1.f : 0.f;                                        \
      float vx0 = (x0 == x0c) ? 1.f : 0.f;                                        \
      float vx1 = (x1 == x1c) ? 1.f : 0.f;                                        \
      float w00 = (1.f - wy) * (1.f - wx) * vy0 * vx0;                            \
      float w01 = (1.f - wy) * wx * vy0 * vx1;                                    \
      float w10 = wy * (1.f - wx) * vy1 * vx0;                                    \
      float w11 = wy * wx * vy1 * vx1;                                            \
      const bf16_t* bg = obase + g * 8;                                           \
      bf16x8 c00 = *(const bf16x8*)(bg + (size_t)(y0c * 64 + x0c) * 152);         \
      bf16x8 c01 = *(const bf16x8*)(bg + (size_t)(y0c * 64 + x1c) * 152);         \
      bf16x8 c10 = *(const bf16x8*)(bg + (size_t)(y1c * 64 + x0c) * 152);         \
      bf16x8 c11 = *(const bf16x8*)(bg + (size_t)(y1c * 64 + x1c) * 152);         \
      bf16x8 o;                                                                   \
      _Pragma("unroll") for (int i = 0; i < 8; i++) {                             \
        float f = w00 * (float)c00[i];                                            \
        f = fmaf(w01, (float)c01[i], f);                                          \
        f = fmaf(w10, (float)c10[i], f);                                          \
        f = fmaf(w11, (float)c11[i], f);                                          \
        o[i] = (bf16_t)f;                                                         \
      }                                                                           \
      *(bf16x8*)(abuf + (CUR)*2688 + r * 168 + g * 8) = o;                        \
    }                                                                             \
  }

  SAMPLE_TAP(0, 0)
  __syncthreads();
  for (int t = 0; t < 9; t++) {
    int cur = t & 1;
    if (t < 8) SAMPLE_TAP(t + 1, cur ^ 1)
    // GEMM on abuf[cur]: 5 kk x 3 n-frags
#pragma unroll
    for (int kk = 0; kk < 5; kk++) {
      int k0 = kk * 32 + q * 8;
      bf16x8 a = *(const bf16x8*)(abuf + cur * 2688 + lr * 168 + k0);
#pragma unroll
      for (int n = 0; n < 3; n++) {
        bf16x8 bf = *(const bf16x8*)(wdb + (size_t)((wid * 3 + n) * 16 + lr) * 1440 + t * 160 + k0);
        acc[n] = mfma16(a, bf, acc[n]);
      }
    }
    __syncthreads();
  }
#pragma unroll
  for (int n = 0; n < 3; n++) {
    int oc = (wid * 3 + n) * 16 + lr;
    if (oc < 152) {
      float inv = bnc[304 + oc], beta = bnc[456 + oc];
#pragma unroll
      for (int i = 0; i < 4; i++) {
        int p = row0 + q * 4 + i;
        float v = fmaxf(acc[n][i], 0.f) * inv + beta;
        a2[(size_t)p * 152 + oc] = (bf16_t)v;
      }
    }
  }
#undef SAMPLE_TAP
}

// ---------------- S4: conv3 1x1 (K=152->160, N=608->640) + bn3 + residual + relu -> out NCHW fp32 ----------------
__global__ __launch_bounds__(256) void s4_conv3(const bf16_t* __restrict__ a2,
                                                const bf16_t* __restrict__ w3b,
                                                const float* __restrict__ bnc,
                                                const float* __restrict__ x,
                                                float* __restrict__ out) {
  int tid = threadIdx.x;
  int wid = tid >> 6, lane = tid & 63, q = lane >> 4, lr = lane & 15;
  int p0 = blockIdx.x * 16;
  int b = p0 >> 12, sp0 = p0 & 4095;
  f32x4 acc[10];
#pragma unroll
  for (int n = 0; n < 10; n++) acc[n] = (f32x4){0.f, 0.f, 0.f, 0.f};
  for (int kk = 0; kk < 5; kk++) {
    int k0 = kk * 32 + q * 8;
    bf16x8 a = (k0 < 152) ? *(const bf16x8*)(a2 + (size_t)(p0 + lr) * 152 + k0) : bzero8();
#pragma unroll
    for (int n = 0; n < 10; n++) {
      bf16x8 bf = *(const bf16x8*)(w3b + (size_t)(wid * 160 + n * 16 + lr) * 160 + k0);
      acc[n] = mfma16(a, bf, acc[n]);
    }
  }
#pragma unroll
  for (int n = 0; n < 10; n++) {
    int oc = wid * 160 + n * 16 + lr;
    if (oc < 608) {
      float inv = bnc[608 + oc], beta = bnc[1216 + oc];
      size_t gi = (((size_t)(b * 608 + oc)) << 12) + sp0 + q * 4;
      f32x4 xr = *(const f32x4*)(x + gi);
      f32x4 o;
#pragma unroll
      for (int i = 0; i < 4; i++) o[i] = fmaxf(acc[n][i] * inv + beta + xr[i], 0.f);
      *(f32x4*)(out + gi) = o;
    }
  }
}

extern "C" void kernel_launch(void* const* d_in, const int* in_sizes, int n_in,
                              void* d_out, int out_size, void* d_ws, size_t ws_size,
                              hipStream_t stream) {
  const float* x = (const float*)d_in[0];
  const float* w1 = (const float*)d_in[1];
  const float* w2 = (const float*)d_in[2];
  const float* wd = (const float*)d_in[3];
  const float* w3 = (const float*)d_in[4];
  const float* g1 = (const float*)d_in[5];
  const float* b1 = (const float*)d_in[6];
  const float* m1 = (const float*)d_in[7];
  const float* v1 = (const float*)d_in[8];
  const float* g2 = (const float*)d_in[9];
  const float* b2 = (const float*)d_in[10];
  const float* m2 = (const float*)d_in[11];
  const float* v2 = (const float*)d_in[12];
  const float* g3 = (const float*)d_in[13];
  const float* b3 = (const float*)d_in[14];
  const float* m3 = (const float*)d_in[15];
  const float* v3 = (const float*)d_in[16];

  char* ws = (char*)d_ws;
  bf16_t* w1b = (bf16_t*)(ws + 0);          // 160*608*2   = 194560
  bf16_t* w2b = (bf16_t*)(ws + 194560);     // 384*1376*2  = 1056768
  bf16_t* wdb = (bf16_t*)(ws + 1251328);    // 192*1440*2  = 552960
  bf16_t* w3b = (bf16_t*)(ws + 1804288);    // 640*160*2   = 204800
  float* bnc = (float*)(ws + 2009088);      // 1824*4      = 7296
  bf16_t* out1 = (bf16_t*)(ws + 2016384);   // 16384*152*2 = 4980736
  float* offs = (float*)(ws + 6997120);     // 16384*344*4 = 22544384
  bf16_t* a2 = (bf16_t*)(ws + 29541504);    // 16384*152*2 = 4980736  end 34522240
  float* out = (float*)d_out;

  prep_weights<<<3924, 256, 0, stream>>>(w1, w2, wd, w3, w1b, w2b, wdb, w3b);
  prep_bn<<<1, 640, 0, stream>>>(g1, b1, m1, v1, g2, b2, m2, v2, g3, b3, m3, v3, bnc);
  s1_conv1<<<512, 256, 0, stream>>>(x, w1b, bnc, out1);
  s2_offs<<<512, 512, 0, stream>>>(out1, w2b, offs);
  s3_dconv<<<1024, 256, 0, stream>>>(out1, offs, wdb, bnc, a2);
  s4_conv3<<<1024, 256, 0, stream>>>(a2, w3b, bnc, x, out);
}

// Round 5
// 173.891 us; speedup vs baseline: 1.1657x; 1.0159x over previous
//
#include <hip/hip_runtime.h>

#define EPSV 1e-5f

typedef __bf16 bf16_t;
typedef __bf16 bf16x8 __attribute__((ext_vector_type(8)));
typedef float f32x4 __attribute__((ext_vector_type(4)));

__device__ inline bf16x8 bzero8() {
  bf16x8 z;
#pragma unroll
  for (int i = 0; i < 8; i++) z[i] = (bf16_t)0.f;
  return z;
}

__device__ inline f32x4 mfma16(bf16x8 a, bf16x8 b, f32x4 c) {
  return __builtin_amdgcn_mfma_f32_16x16x32_bf16(a, b, c, 0, 0, 0);
}

// ---------------- weight prep: fp32 -> bf16, padded + reordered ----------------
// w1b [160][608]        (row=oc, k=ic)               oc>=152 zero
// w2b [384][1376]       (row=oc, k=tap*152+ic)       pads zero
// wdb [192][1440]       (row=o,  k=tap*160+ic)       pads zero (per-tap k-slice padded to 160)
// w3b [640][160]        (row=oc, k=ic)               k>=152 / oc>=608 zero
#define W1E (160 * 608)
#define W2E (384 * 1376)
#define WDE (192 * 1440)
#define W3E (640 * 160)

__global__ __launch_bounds__(256) void prep_weights(
    const float* __restrict__ w1, const float* __restrict__ w2,
    const float* __restrict__ wd, const float* __restrict__ w3,
    bf16_t* __restrict__ w1b, bf16_t* __restrict__ w2b,
    bf16_t* __restrict__ wdb, bf16_t* __restrict__ w3b) {
  int i = blockIdx.x * 256 + threadIdx.x;
  float v = 0.f;
  if (i < W1E) {
    int oc = i / 608, ic = i % 608;
    if (oc < 152) v = w1[oc * 608 + ic];
    w1b[i] = (bf16_t)v;
  } else if (i < W1E + W2E) {
    int j = i - W1E;
    int oc = j / 1376, k = j % 1376;
    if (oc < 342 && k < 1368) {
      int t = k / 152, ic = k % 152;
      v = w2[(oc * 152 + ic) * 9 + t];
    }
    w2b[j] = (bf16_t)v;
  } else if (i < W1E + W2E + WDE) {
    int j = i - W1E - W2E;
    int o = j / 1440, k = j % 1440;
    int t = k / 160, ic = k % 160;
    if (o < 152 && ic < 152) v = wd[(o * 152 + ic) * 9 + t];
    wdb[j] = (bf16_t)v;
  } else if (i < W1E + W2E + WDE + W3E) {
    int j = i - W1E - W2E - WDE;
    int oc = j / 160, ic = j % 160;
    if (oc < 608 && ic < 152) v = w3[oc * 152 + ic];
    w3b[j] = (bf16_t)v;
  }
}

// bnc layout: [0,152) inv1, [152,304) beta1, [304,456) inv2, [456,608) beta2,
//             [608,1216) inv3, [1216,1824) beta3
__global__ void prep_bn(const float* g1, const float* b1, const float* m1, const float* v1,
                        const float* g2, const float* b2, const float* m2, const float* v2,
                        const float* g3, const float* b3, const float* m3, const float* v3,
                        float* __restrict__ bnc) {
  int i = threadIdx.x;
  if (i < 152) {
    float inv = g1[i] / sqrtf(v1[i] + EPSV);
    bnc[i] = inv;
    bnc[152 + i] = b1[i] - m1[i] * inv;
    float inv2 = g2[i] / sqrtf(v2[i] + EPSV);
    bnc[304 + i] = inv2;
    bnc[456 + i] = b2[i] - m2[i] * inv2;
  }
  if (i < 608) {
    float inv3 = g3[i] / sqrtf(v3[i] + EPSV);
    bnc[608 + i] = inv3;
    bnc[1216 + i] = b3[i] - m3[i] * inv3;
  }
}

// ---------------- S1: conv1 1x1 (K=608,N=152) + relu + bn1 -> out1 NHWC bf16 ----------------
__global__ __launch_bounds__(256) void s1_conv1(const float* __restrict__ x,
                                                const bf16_t* __restrict__ w1b,
                                                const float* __restrict__ bnc,
                                                bf16_t* __restrict__ out1) {
  __shared__ bf16_t t1[32 * 616];  // 38.5 KB
  int tid = threadIdx.x;
  int px0 = blockIdx.x * 32;
  int b = px0 >> 12, sp0 = px0 & 4095;
  for (int task = tid; task < 608 * 8; task += 256) {
    int c = task >> 3, i4 = task & 7;
    f32x4 v = *(const f32x4*)(x + (((size_t)(b * 608 + c)) << 12) + sp0 + i4 * 4);
#pragma unroll
    for (int i = 0; i < 4; i++) t1[(i4 * 4 + i) * 616 + c] = (bf16_t)v[i];
  }
  __syncthreads();
  int wid = tid >> 6, lane = tid & 63, q = lane >> 4, lr = lane & 15;
  int mw = wid & 1, nw = wid >> 1;  // 2M x 2N
  f32x4 acc[5];
#pragma unroll
  for (int n = 0; n < 5; n++) acc[n] = (f32x4){0.f, 0.f, 0.f, 0.f};
  for (int kk = 0; kk < 19; kk++) {
    int k0 = kk * 32 + q * 8;
    bf16x8 a = *(const bf16x8*)(t1 + (mw * 16 + lr) * 616 + k0);
#pragma unroll
    for (int n = 0; n < 5; n++) {
      bf16x8 bf = *(const bf16x8*)(w1b + (nw * 80 + n * 16 + lr) * 608 + k0);
      acc[n] = mfma16(a, bf, acc[n]);
    }
  }
#pragma unroll
  for (int n = 0; n < 5; n++) {
    int oc = nw * 80 + n * 16 + lr;
    if (oc < 152) {
      float inv = bnc[oc], beta = bnc[152 + oc];
#pragma unroll
      for (int i = 0; i < 4; i++) {
        int p = px0 + mw * 16 + q * 4 + i;
        float v = fmaxf(acc[n][i], 0.f) * inv + beta;
        out1[(size_t)p * 152 + oc] = (bf16_t)v;
      }
    }
  }
}

// ---------------- S2: offset conv 3x3 (K=1368->1376, N=342->384) -> offs fp32 [pix][col] ----------------
// natural col order (col = g*18 + t*2 + c) -> coalesced 64B writes.
// 256 thr / 32 px; halo [3][34][156] (pad 156: 2-way-free banks); 4 waves x (2m x 6n);
// 1-deep B prefetch; __launch_bounds__(256,5) -> 5 blocks/CU.
__global__ __launch_bounds__(256, 5) void s2_offs(const bf16_t* __restrict__ out1,
                                                  const bf16_t* __restrict__ w2b,
                                                  float* __restrict__ offs) {
  __shared__ bf16_t t2[3 * 34 * 156];  // 31.8 KB
  int tid = threadIdx.x;
  int xh = blockIdx.x & 1, y = (blockIdx.x >> 1) & 63, b = blockIdx.x >> 7;
  const bf16_t* ob = out1 + (((size_t)b) << 12) * 152;
  int x0 = xh * 32 - 1;
  // stage 3 rows (y-1..y+1) x 34 px x 152 ch, OOB -> 0
  for (int task = tid; task < 3 * 34 * 19; task += 256) {
    int j = task / 646, r = task % 646;
    int xi = r / 19, cb = r % 19;
    int yy = y + j - 1, xx = x0 + xi;
    bf16x8 v = bzero8();
    if (yy >= 0 && yy < 64 && xx >= 0 && xx < 64)
      v = *(const bf16x8*)(ob + (size_t)(yy * 64 + xx) * 152 + cb * 8);
    *(bf16x8*)(t2 + (j * 34 + xi) * 156 + cb * 8) = v;
  }
  __syncthreads();
  int wid = tid >> 6, lane = tid & 63, q = lane >> 4, lr = lane & 15;
  f32x4 acc[2][6];
#pragma unroll
  for (int m = 0; m < 2; m++)
#pragma unroll
    for (int n = 0; n < 6; n++) acc[m][n] = (f32x4){0.f, 0.f, 0.f, 0.f};
  // B row base for this wave's 6 n-frags
  const bf16_t* wb = w2b + (size_t)lr * 1376;
  bf16x8 bcur[6];
#pragma unroll
  for (int n = 0; n < 6; n++)
    bcur[n] = *(const bf16x8*)(wb + (size_t)(wid * 96 + n * 16) * 1376 + q * 8);
  for (int kk = 0; kk < 43; kk++) {
    int k0 = kk * 32 + q * 8;
    bf16x8 bnx[6];
    if (kk < 42) {
      int k1 = k0 + 32;
#pragma unroll
      for (int n = 0; n < 6; n++)
        bnx[n] = *(const bf16x8*)(wb + (size_t)(wid * 96 + n * 16) * 1376 + k1);
    }
    bf16x8 a[2];
    if (k0 < 1368) {
      int t = k0 / 152, c0 = k0 - t * 152;
      int dy = t / 3, dxp1 = t - dy * 3;
#pragma unroll
      for (int m = 0; m < 2; m++)
        a[m] = *(const bf16x8*)(t2 + (dy * 34 + m * 16 + lr + dxp1) * 156 + c0);
    } else {
      a[0] = bzero8();
      a[1] = bzero8();
    }
#pragma unroll
    for (int n = 0; n < 6; n++)
#pragma unroll
      for (int m = 0; m < 2; m++) acc[m][n] = mfma16(a[m], bcur[n], acc[m][n]);
#pragma unroll
    for (int n = 0; n < 6; n++) bcur[n] = bnx[n];
  }
#pragma unroll
  for (int n = 0; n < 6; n++) {
    int col = wid * 96 + n * 16 + lr;
    if (col < 342) {
#pragma unroll
      for (int m = 0; m < 2; m++)
#pragma unroll
        for (int i = 0; i < 4; i++) {
          int p = (b << 12) + y * 64 + xh * 32 + m * 16 + q * 4 + i;
          offs[(size_t)p * 344 + col] = acc[m][n][i];
        }
    }
  }
}

// ---------------- S3: deform sample + GEMM, tap-pipelined ----------------
// LDS: offsets [16][344] f32 (22 KB) + A double-buffer [2][16][168] bf16 (10.5 KB) = 32 KB
// offs natural layout: (t,g) pair at col g*18 + t*2
__global__ __launch_bounds__(256, 4) void s3_dconv(const bf16_t* __restrict__ out1,
                                                   const float* __restrict__ offs,
                                                   const bf16_t* __restrict__ wdb,
                                                   const float* __restrict__ bnc,
                                                   bf16_t* __restrict__ a2) {
  __shared__ float olds[16 * 344];       // 22016 B
  __shared__ bf16_t abuf[2 * 16 * 168];  // 10752 B
  int tid = threadIdx.x;
  int row0 = blockIdx.x * 16;
  int bb = row0 >> 12;
  const bf16_t* obase = out1 + (((size_t)bb << 12) * 152);
  if (tid < 64) {
    int cur = tid >> 5, r = (tid >> 1) & 15, ch = tid & 1;
    *(bf16x8*)(abuf + cur * 2688 + r * 168 + 152 + ch * 8) = bzero8();
  }
  for (int task = tid; task < 16 * 86; task += 256) {
    int r = task / 86, cc = task - r * 86;
    *(f32x4*)(olds + r * 344 + cc * 4) =
        *(const f32x4*)(offs + (size_t)(row0 + r) * 344 + cc * 4);
  }
  __syncthreads();

  int wid = tid >> 6, lane = tid & 63, q = lane >> 4, lr = lane & 15;
  f32x4 acc[3];
#pragma unroll
  for (int n = 0; n < 3; n++) acc[n] = (f32x4){0.f, 0.f, 0.f, 0.f};

#define SAMPLE_TAP(T, CUR)                                                        \
  {                                                                               \
    int t_ = (T);                                                                 \
    int ky = t_ / 3, kx = t_ - ky * 3;                                            \
    for (int task = tid; task < 304; task += 256) {                               \
      int r = task / 19, g = task - r * 19;                                       \
      int p = row0 + r;                                                           \
      int y = (p >> 6) & 63, xc = p & 63;                                         \
      float2 ov = *(const float2*)(olds + r * 344 + g * 18 + t_ * 2);             \
      float ys = (float)(y - 1 + ky) + ov.x;                                      \
      float xs = (float)(xc - 1 + kx) + ov.y;                                     \
      float y0f = floorf(ys), x0f = floorf(xs);                                   \
      float wy = ys - y0f, wx = xs - x0f;                                         \
      int y0 = (int)y0f, x0 = (int)x0f;                                           \
      int y1 = y0 + 1, x1 = x0 + 1;                                               \
      int y0c = min(max(y0, 0), 63), x0c = min(max(x0, 0), 63);                   \
      int y1c = min(max(y1, 0), 63), x1c = min(max(x1, 0), 63);                   \
      float vy0 = (y0 == y0c) ? 1.f : 0.f;                                        \
      float vy1 = (y1 == y1c) ? 1.f : 0.f;                                        \
      float vx0 = (x0 == x0c) ? 1.f : 0.f;                                        \
      float vx1 = (x1 == x1c) ? 1.f : 0.f;                                        \
      float w00 = (1.f - wy) * (1.f - wx) * vy0 * vx0;                            \
      float w01 = (1.f - wy) * wx * vy0 * vx1;                                    \
      float w10 = wy * (1.f - wx) * vy1 * vx0;                                    \
      float w11 = wy * wx * vy1 * vx1;                                            \
      const bf16_t* bg = obase + g * 8;                                           \
      bf16x8 c00 = *(const bf16x8*)(bg + (size_t)(y0c * 64 + x0c) * 152);         \
      bf16x8 c01 = *(const bf16x8*)(bg + (size_t)(y0c * 64 + x1c) * 152);         \
      bf16x8 c10 = *(const bf16x8*)(bg + (size_t)(y1c * 64 + x0c) * 152);         \
      bf16x8 c11 = *(const bf16x8*)(bg + (size_t)(y1c * 64 + x1c) * 152);         \
      bf16x8 o;                                                                   \
      _Pragma("unroll") for (int i = 0; i < 8; i++) {                             \
        float f = w00 * (float)c00[i];                                            \
        f = fmaf(w01, (float)c01[i], f);                                          \
        f = fmaf(w10, (float)c10[i], f);                                          \
        f = fmaf(w11, (float)c11[i], f);                                          \
        o[i] = (bf16_t)f;                                                         \
      }                                                                           \
      *(bf16x8*)(abuf + (CUR)*2688 + r * 168 + g * 8) = o;                        \
    }                                                                             \
  }

  SAMPLE_TAP(0, 0)
  __syncthreads();
  for (int t = 0; t < 9; t++) {
    int cur = t & 1;
    if (t < 8) SAMPLE_TAP(t + 1, cur ^ 1)
#pragma unroll
    for (int kk = 0; kk < 5; kk++) {
      int k0 = kk * 32 + q * 8;
      bf16x8 a = *(const bf16x8*)(abuf + cur * 2688 + lr * 168 + k0);
#pragma unroll
      for (int n = 0; n < 3; n++) {
        bf16x8 bf = *(const bf16x8*)(wdb + (size_t)((wid * 3 + n) * 16 + lr) * 1440 + t * 160 + k0);
        acc[n] = mfma16(a, bf, acc[n]);
      }
    }
    __syncthreads();
  }
#pragma unroll
  for (int n = 0; n < 3; n++) {
    int oc = (wid * 3 + n) * 16 + lr;
    if (oc < 152) {
      float inv = bnc[304 + oc], beta = bnc[456 + oc];
#pragma unroll
      for (int i = 0; i < 4; i++) {
        int p = row0 + q * 4 + i;
        float v = fmaxf(acc[n][i], 0.f) * inv + beta;
        a2[(size_t)p * 152 + oc] = (bf16_t)v;
      }
    }
  }
#undef SAMPLE_TAP
}

// ---------------- S4: conv3 1x1 (K=152->160, N=608->640) + bn3 + residual + relu -> out NCHW fp32 ----------------
__global__ __launch_bounds__(256) void s4_conv3(const bf16_t* __restrict__ a2,
                                                const bf16_t* __restrict__ w3b,
                                                const float* __restrict__ bnc,
                                                const float* __restrict__ x,
                                                float* __restrict__ out) {
  int tid = threadIdx.x;
  int wid = tid >> 6, lane = tid & 63, q = lane >> 4, lr = lane & 15;
  int p0 = blockIdx.x * 16;
  int b = p0 >> 12, sp0 = p0 & 4095;
  f32x4 acc[10];
#pragma unroll
  for (int n = 0; n < 10; n++) acc[n] = (f32x4){0.f, 0.f, 0.f, 0.f};
  for (int kk = 0; kk < 5; kk++) {
    int k0 = kk * 32 + q * 8;
    bf16x8 a = (k0 < 152) ? *(const bf16x8*)(a2 + (size_t)(p0 + lr) * 152 + k0) : bzero8();
#pragma unroll
    for (int n = 0; n < 10; n++) {
      bf16x8 bf = *(const bf16x8*)(w3b + (size_t)(wid * 160 + n * 16 + lr) * 160 + k0);
      acc[n] = mfma16(a, bf, acc[n]);
    }
  }
#pragma unroll
  for (int n = 0; n < 10; n++) {
    int oc = wid * 160 + n * 16 + lr;
    if (oc < 608) {
      float inv = bnc[608 + oc], beta = bnc[1216 + oc];
      size_t gi = (((size_t)(b * 608 + oc)) << 12) + sp0 + q * 4;
      f32x4 xr = *(const f32x4*)(x + gi);
      f32x4 o;
#pragma unroll
      for (int i = 0; i < 4; i++) o[i] = fmaxf(acc[n][i] * inv + beta + xr[i], 0.f);
      *(f32x4*)(out + gi) = o;
    }
  }
}

extern "C" void kernel_launch(void* const* d_in, const int* in_sizes, int n_in,
                              void* d_out, int out_size, void* d_ws, size_t ws_size,
                              hipStream_t stream) {
  const float* x = (const float*)d_in[0];
  const float* w1 = (const float*)d_in[1];
  const float* w2 = (const float*)d_in[2];
  const float* wd = (const float*)d_in[3];
  const float* w3 = (const float*)d_in[4];
  const float* g1 = (const float*)d_in[5];
  const float* b1 = (const float*)d_in[6];
  const float* m1 = (const float*)d_in[7];
  const float* v1 = (const float*)d_in[8];
  const float* g2 = (const float*)d_in[9];
  const float* b2 = (const float*)d_in[10];
  const float* m2 = (const float*)d_in[11];
  const float* v2 = (const float*)d_in[12];
  const float* g3 = (const float*)d_in[13];
  const float* b3 = (const float*)d_in[14];
  const float* m3 = (const float*)d_in[15];
  const float* v3 = (const float*)d_in[16];

  char* ws = (char*)d_ws;
  bf16_t* w1b = (bf16_t*)(ws + 0);          // 160*608*2   = 194560
  bf16_t* w2b = (bf16_t*)(ws + 194560);     // 384*1376*2  = 1056768
  bf16_t* wdb = (bf16_t*)(ws + 1251328);    // 192*1440*2  = 552960
  bf16_t* w3b = (bf16_t*)(ws + 1804288);    // 640*160*2   = 204800
  float* bnc = (float*)(ws + 2009088);      // 1824*4      = 7296
  bf16_t* out1 = (bf16_t*)(ws + 2016384);   // 16384*152*2 = 4980736
  float* offs = (float*)(ws + 6997120);     // 16384*344*4 = 22544384
  bf16_t* a2 = (bf16_t*)(ws + 29541504);    // 16384*152*2 = 4980736  end 34522240
  float* out = (float*)d_out;

  prep_weights<<<3924, 256, 0, stream>>>(w1, w2, wd, w3, w1b, w2b, wdb, w3b);
  prep_bn<<<1, 640, 0, stream>>>(g1, b1, m1, v1, g2, b2, m2, v2, g3, b3, m3, v3, bnc);
  s1_conv1<<<512, 256, 0, stream>>>(x, w1b, bnc, out1);
  s2_offs<<<512, 256, 0, stream>>>(out1, w2b, offs);
  s3_dconv<<<1024, 256, 0, stream>>>(out1, offs, wdb, bnc, a2);
  s4_conv3<<<1024, 256, 0, stream>>>(a2, w3b, bnc, x, out);
}

// Round 6
// 163.645 us; speedup vs baseline: 1.2387x; 1.0626x over previous
//
#include <hip/hip_runtime.h>

#define EPSV 1e-5f

typedef __bf16 bf16_t;
typedef __bf16 bf16x8 __attribute__((ext_vector_type(8)));
typedef float f32x4 __attribute__((ext_vector_type(4)));

__device__ inline bf16x8 bzero8() {
  bf16x8 z;
#pragma unroll
  for (int i = 0; i < 8; i++) z[i] = (bf16_t)0.f;
  return z;
}

__device__ inline f32x4 mfma16(bf16x8 a, bf16x8 b, f32x4 c) {
  return __builtin_amdgcn_mfma_f32_16x16x32_bf16(a, b, c, 0, 0, 0);
}

// ---------------- weight prep: fp32 -> bf16, padded + reordered ----------------
// w1b [160][608]        (row=oc, k=ic)               oc>=152 zero
// w2b [384][1376]       (row=oc, k=tap*152+ic)       pads zero
// wdb [192][1440]       (row=o,  k=tap*160+ic)       pads zero (per-tap k-slice padded to 160)
// w3b [640][160]        (row=oc, k=ic)               k>=152 / oc>=608 zero
#define W1E (160 * 608)
#define W2E (384 * 1376)
#define WDE (192 * 1440)
#define W3E (640 * 160)

__global__ __launch_bounds__(256) void prep_weights(
    const float* __restrict__ w1, const float* __restrict__ w2,
    const float* __restrict__ wd, const float* __restrict__ w3,
    bf16_t* __restrict__ w1b, bf16_t* __restrict__ w2b,
    bf16_t* __restrict__ wdb, bf16_t* __restrict__ w3b) {
  int i = blockIdx.x * 256 + threadIdx.x;
  float v = 0.f;
  if (i < W1E) {
    int oc = i / 608, ic = i % 608;
    if (oc < 152) v = w1[oc * 608 + ic];
    w1b[i] = (bf16_t)v;
  } else if (i < W1E + W2E) {
    int j = i - W1E;
    int oc = j / 1376, k = j % 1376;
    if (oc < 342 && k < 1368) {
      int t = k / 152, ic = k % 152;
      v = w2[(oc * 152 + ic) * 9 + t];
    }
    w2b[j] = (bf16_t)v;
  } else if (i < W1E + W2E + WDE) {
    int j = i - W1E - W2E;
    int o = j / 1440, k = j % 1440;
    int t = k / 160, ic = k % 160;
    if (o < 152 && ic < 152) v = wd[(o * 152 + ic) * 9 + t];
    wdb[j] = (bf16_t)v;
  } else if (i < W1E + W2E + WDE + W3E) {
    int j = i - W1E - W2E - WDE;
    int oc = j / 160, ic = j % 160;
    if (oc < 608 && ic < 152) v = w3[oc * 152 + ic];
    w3b[j] = (bf16_t)v;
  }
}

// bnc layout: [0,152) inv1, [152,304) beta1, [304,456) inv2, [456,608) beta2,
//             [608,1216) inv3, [1216,1824) beta3
__global__ void prep_bn(const float* g1, const float* b1, const float* m1, const float* v1,
                        const float* g2, const float* b2, const float* m2, const float* v2,
                        const float* g3, const float* b3, const float* m3, const float* v3,
                        float* __restrict__ bnc) {
  int i = threadIdx.x;
  if (i < 152) {
    float inv = g1[i] / sqrtf(v1[i] + EPSV);
    bnc[i] = inv;
    bnc[152 + i] = b1[i] - m1[i] * inv;
    float inv2 = g2[i] / sqrtf(v2[i] + EPSV);
    bnc[304 + i] = inv2;
    bnc[456 + i] = b2[i] - m2[i] * inv2;
  }
  if (i < 608) {
    float inv3 = g3[i] / sqrtf(v3[i] + EPSV);
    bnc[608 + i] = inv3;
    bnc[1216 + i] = b3[i] - m3[i] * inv3;
  }
}

// ---------------- S1: conv1 1x1 (K=608,N=152) + relu + bn1 -> out1 NHWC bf16 ----------------
__global__ __launch_bounds__(256) void s1_conv1(const float* __restrict__ x,
                                                const bf16_t* __restrict__ w1b,
                                                const float* __restrict__ bnc,
                                                bf16_t* __restrict__ out1) {
  __shared__ bf16_t t1[32 * 616];  // 38.5 KB
  int tid = threadIdx.x;
  int px0 = blockIdx.x * 32;
  int b = px0 >> 12, sp0 = px0 & 4095;
  for (int task = tid; task < 608 * 8; task += 256) {
    int c = task >> 3, i4 = task & 7;
    f32x4 v = *(const f32x4*)(x + (((size_t)(b * 608 + c)) << 12) + sp0 + i4 * 4);
#pragma unroll
    for (int i = 0; i < 4; i++) t1[(i4 * 4 + i) * 616 + c] = (bf16_t)v[i];
  }
  __syncthreads();
  int wid = tid >> 6, lane = tid & 63, q = lane >> 4, lr = lane & 15;
  int mw = wid & 1, nw = wid >> 1;  // 2M x 2N
  f32x4 acc[5];
#pragma unroll
  for (int n = 0; n < 5; n++) acc[n] = (f32x4){0.f, 0.f, 0.f, 0.f};
  for (int kk = 0; kk < 19; kk++) {
    int k0 = kk * 32 + q * 8;
    bf16x8 a = *(const bf16x8*)(t1 + (mw * 16 + lr) * 616 + k0);
#pragma unroll
    for (int n = 0; n < 5; n++) {
      bf16x8 bf = *(const bf16x8*)(w1b + (nw * 80 + n * 16 + lr) * 608 + k0);
      acc[n] = mfma16(a, bf, acc[n]);
    }
  }
#pragma unroll
  for (int n = 0; n < 5; n++) {
    int oc = nw * 80 + n * 16 + lr;
    if (oc < 152) {
      float inv = bnc[oc], beta = bnc[152 + oc];
#pragma unroll
      for (int i = 0; i < 4; i++) {
        int p = px0 + mw * 16 + q * 4 + i;
        float v = fmaxf(acc[n][i], 0.f) * inv + beta;
        out1[(size_t)p * 152 + oc] = (bf16_t)v;
      }
    }
  }
}

// ---------------- S2: offset conv 3x3 (K=1368->1376, N=342->384) -> offs fp32 [pix][col] ----------------
// N-split: block = 32 px x 192 cols (nh = blockIdx&1), grid 1024 -> 4 blocks/CU.
// halo [3][34][156] in LDS; 4 waves x (2m x 3n); fully-unrolled k-loop so the
// compiler hoists B loads into the 128-VGPR budget (launch_bounds(256,4)).
__global__ __launch_bounds__(256, 4) void s2_offs(const bf16_t* __restrict__ out1,
                                                  const bf16_t* __restrict__ w2b,
                                                  float* __restrict__ offs) {
  __shared__ bf16_t t2[3 * 34 * 156];  // 31.8 KB
  int tid = threadIdx.x;
  int nh = blockIdx.x & 1;
  int rest = blockIdx.x >> 1;
  int xh = rest & 1, y = (rest >> 1) & 63, b = rest >> 7;
  const bf16_t* ob = out1 + (((size_t)b) << 12) * 152;
  int x0 = xh * 32 - 1;
  // stage 3 rows (y-1..y+1) x 34 px x 152 ch, OOB -> 0
  for (int task = tid; task < 3 * 34 * 19; task += 256) {
    int j = task / 646, r = task % 646;
    int xi = r / 19, cb = r % 19;
    int yy = y + j - 1, xx = x0 + xi;
    bf16x8 v = bzero8();
    if (yy >= 0 && yy < 64 && xx >= 0 && xx < 64)
      v = *(const bf16x8*)(ob + (size_t)(yy * 64 + xx) * 152 + cb * 8);
    *(bf16x8*)(t2 + (j * 34 + xi) * 156 + cb * 8) = v;
  }
  __syncthreads();
  int wid = tid >> 6, lane = tid & 63, q = lane >> 4, lr = lane & 15;
  int ncol0 = nh * 192 + wid * 48;  // this wave's 3 n-frags
  f32x4 acc[2][3];
#pragma unroll
  for (int m = 0; m < 2; m++)
#pragma unroll
    for (int n = 0; n < 3; n++) acc[m][n] = (f32x4){0.f, 0.f, 0.f, 0.f};
  const bf16_t* wb = w2b + (size_t)(ncol0 + lr) * 1376;
#pragma unroll
  for (int kk = 0; kk < 43; kk++) {
    int k0 = kk * 32 + q * 8;
    bf16x8 bfr[3];
#pragma unroll
    for (int n = 0; n < 3; n++)
      bfr[n] = *(const bf16x8*)(wb + (size_t)(n * 16) * 1376 + k0);
    bf16x8 a[2];
    if (k0 < 1368) {
      int t = k0 / 152, c0 = k0 - t * 152;
      int dy = t / 3, dxp1 = t - dy * 3;
#pragma unroll
      for (int m = 0; m < 2; m++)
        a[m] = *(const bf16x8*)(t2 + (dy * 34 + m * 16 + lr + dxp1) * 156 + c0);
    } else {
      a[0] = bzero8();
      a[1] = bzero8();
    }
#pragma unroll
    for (int n = 0; n < 3; n++)
#pragma unroll
      for (int m = 0; m < 2; m++) acc[m][n] = mfma16(a[m], bfr[n], acc[m][n]);
  }
#pragma unroll
  for (int n = 0; n < 3; n++) {
    int col = ncol0 + n * 16 + lr;
    if (col < 342) {
#pragma unroll
      for (int m = 0; m < 2; m++)
#pragma unroll
        for (int i = 0; i < 4; i++) {
          int p = (b << 12) + y * 64 + xh * 32 + m * 16 + q * 4 + i;
          offs[(size_t)p * 344 + col] = acc[m][n][i];
        }
    }
  }
}

// ---------------- S3: deform sample + GEMM, tap-pipelined ----------------
// LDS: offsets [16][344] f32 (22 KB) + A double-buffer [2][16][168] bf16 (10.5 KB) = 32 KB
// offs natural layout: (t,g) pair at col g*18 + t*2
__global__ __launch_bounds__(256, 4) void s3_dconv(const bf16_t* __restrict__ out1,
                                                   const float* __restrict__ offs,
                                                   const bf16_t* __restrict__ wdb,
                                                   const float* __restrict__ bnc,
                                                   bf16_t* __restrict__ a2) {
  __shared__ float olds[16 * 344];       // 22016 B
  __shared__ bf16_t abuf[2 * 16 * 168];  // 10752 B
  int tid = threadIdx.x;
  int row0 = blockIdx.x * 16;
  int bb = row0 >> 12;
  const bf16_t* obase = out1 + (((size_t)bb << 12) * 152);
  if (tid < 64) {
    int cur = tid >> 5, r = (tid >> 1) & 15, ch = tid & 1;
    *(bf16x8*)(abuf + cur * 2688 + r * 168 + 152 + ch * 8) = bzero8();
  }
  for (int task = tid; task < 16 * 86; task += 256) {
    int r = task / 86, cc = task - r * 86;
    *(f32x4*)(olds + r * 344 + cc * 4) =
        *(const f32x4*)(offs + (size_t)(row0 + r) * 344 + cc * 4);
  }
  __syncthreads();

  int wid = tid >> 6, lane = tid & 63, q = lane >> 4, lr = lane & 15;
  f32x4 acc[3];
#pragma unroll
  for (int n = 0; n < 3; n++) acc[n] = (f32x4){0.f, 0.f, 0.f, 0.f};

#define SAMPLE_TAP(T, CUR)                                                        \
  {                                                                               \
    int t_ = (T);                                                                 \
    int ky = t_ / 3, kx = t_ - ky * 3;                                            \
    for (int task = tid; task < 304; task += 256) {                               \
      int r = task / 19, g = task - r * 19;                                       \
      int p = row0 + r;                                                           \
      int y = (p >> 6) & 63, xc = p & 63;                                         \
      float2 ov = *(const float2*)(olds + r * 344 + g * 18 + t_ * 2);             \
      float ys = (float)(y - 1 + ky) + ov.x;                                      \
      float xs = (float)(xc - 1 + kx) + ov.y;                                     \
      float y0f = floorf(ys), x0f = floorf(xs);                                   \
      float wy = ys - y0f, wx = xs - x0f;                                         \
      int y0 = (int)y0f, x0 = (int)x0f;                                           \
      int y1 = y0 + 1, x1 = x0 + 1;                                               \
      int y0c = min(max(y0, 0), 63), x0c = min(max(x0, 0), 63);                   \
      int y1c = min(max(y1, 0), 63), x1c = min(max(x1, 0), 63);                   \
      float vy0 = (y0 == y0c) ? 1.f : 0.f;                                        \
      float vy1 = (y1 == y1c) ? 1.f : 0.f;                                        \
      float vx0 = (x0 == x0c) ? 1.f : 0.f;                                        \
      float vx1 = (x1 == x1c) ? 1.f : 0.f;                                        \
      float w00 = (1.f - wy) * (1.f - wx) * vy0 * vx0;                            \
      float w01 = (1.f - wy) * wx * vy0 * vx1;                                    \
      float w10 = wy * (1.f - wx) * vy1 * vx0;                                    \
      float w11 = wy * wx * vy1 * vx1;                                            \
      const bf16_t* bg = obase + g * 8;                                           \
      bf16x8 c00 = *(const bf16x8*)(bg + (size_t)(y0c * 64 + x0c) * 152);         \
      bf16x8 c01 = *(const bf16x8*)(bg + (size_t)(y0c * 64 + x1c) * 152);         \
      bf16x8 c10 = *(const bf16x8*)(bg + (size_t)(y1c * 64 + x0c) * 152);         \
      bf16x8 c11 = *(const bf16x8*)(bg + (size_t)(y1c * 64 + x1c) * 152);         \
      bf16x8 o;                                                                   \
      _Pragma("unroll") for (int i = 0; i < 8; i++) {                             \
        float f = w00 * (float)c00[i];                                            \
        f = fmaf(w01, (float)c01[i], f);                                          \
        f = fmaf(w10, (float)c10[i], f);                                          \
        f = fmaf(w11, (float)c11[i], f);                                          \
        o[i] = (bf16_t)f;                                                         \
      }                                                                           \
      *(bf16x8*)(abuf + (CUR)*2688 + r * 168 + g * 8) = o;                        \
    }                                                                             \
  }

  SAMPLE_TAP(0, 0)
  __syncthreads();
  for (int t = 0; t < 9; t++) {
    int cur = t & 1;
    if (t < 8) SAMPLE_TAP(t + 1, cur ^ 1)
#pragma unroll
    for (int kk = 0; kk < 5; kk++) {
      int k0 = kk * 32 + q * 8;
      bf16x8 a = *(const bf16x8*)(abuf + cur * 2688 + lr * 168 + k0);
#pragma unroll
      for (int n = 0; n < 3; n++) {
        bf16x8 bf = *(const bf16x8*)(wdb + (size_t)((wid * 3 + n) * 16 + lr) * 1440 + t * 160 + k0);
        acc[n] = mfma16(a, bf, acc[n]);
      }
    }
    __syncthreads();
  }
#pragma unroll
  for (int n = 0; n < 3; n++) {
    int oc = (wid * 3 + n) * 16 + lr;
    if (oc < 152) {
      float inv = bnc[304 + oc], beta = bnc[456 + oc];
#pragma unroll
      for (int i = 0; i < 4; i++) {
        int p = row0 + q * 4 + i;
        float v = fmaxf(acc[n][i], 0.f) * inv + beta;
        a2[(size_t)p * 152 + oc] = (bf16_t)v;
      }
    }
  }
#undef SAMPLE_TAP
}

// ---------------- S4: conv3 1x1 (K=152->160, N=608->640) + bn3 + residual + relu -> out NCHW fp32 ----------------
__global__ __launch_bounds__(256) void s4_conv3(const bf16_t* __restrict__ a2,
                                                const bf16_t* __restrict__ w3b,
                                                const float* __restrict__ bnc,
                                                const float* __restrict__ x,
                                                float* __restrict__ out) {
  int tid = threadIdx.x;
  int wid = tid >> 6, lane = tid & 63, q = lane >> 4, lr = lane & 15;
  int p0 = blockIdx.x * 16;
  int b = p0 >> 12, sp0 = p0 & 4095;
  f32x4 acc[10];
#pragma unroll
  for (int n = 0; n < 10; n++) acc[n] = (f32x4){0.f, 0.f, 0.f, 0.f};
  for (int kk = 0; kk < 5; kk++) {
    int k0 = kk * 32 + q * 8;
    bf16x8 a = (k0 < 152) ? *(const bf16x8*)(a2 + (size_t)(p0 + lr) * 152 + k0) : bzero8();
#pragma unroll
    for (int n = 0; n < 10; n++) {
      bf16x8 bf = *(const bf16x8*)(w3b + (size_t)(wid * 160 + n * 16 + lr) * 160 + k0);
      acc[n] = mfma16(a, bf, acc[n]);
    }
  }
#pragma unroll
  for (int n = 0; n < 10; n++) {
    int oc = wid * 160 + n * 16 + lr;
    if (oc < 608) {
      float inv = bnc[608 + oc], beta = bnc[1216 + oc];
      size_t gi = (((size_t)(b * 608 + oc)) << 12) + sp0 + q * 4;
      f32x4 xr = *(const f32x4*)(x + gi);
      f32x4 o;
#pragma unroll
      for (int i = 0; i < 4; i++) o[i] = fmaxf(acc[n][i] * inv + beta + xr[i], 0.f);
      *(f32x4*)(out + gi) = o;
    }
  }
}

extern "C" void kernel_launch(void* const* d_in, const int* in_sizes, int n_in,
                              void* d_out, int out_size, void* d_ws, size_t ws_size,
                              hipStream_t stream) {
  const float* x = (const float*)d_in[0];
  const float* w1 = (const float*)d_in[1];
  const float* w2 = (const float*)d_in[2];
  const float* wd = (const float*)d_in[3];
  const float* w3 = (const float*)d_in[4];
  const float* g1 = (const float*)d_in[5];
  const float* b1 = (const float*)d_in[6];
  const float* m1 = (const float*)d_in[7];
  const float* v1 = (const float*)d_in[8];
  const float* g2 = (const float*)d_in[9];
  const float* b2 = (const float*)d_in[10];
  const float* m2 = (const float*)d_in[11];
  const float* v2 = (const float*)d_in[12];
  const float* g3 = (const float*)d_in[13];
  const float* b3 = (const float*)d_in[14];
  const float* m3 = (const float*)d_in[15];
  const float* v3 = (const float*)d_in[16];

  char* ws = (char*)d_ws;
  bf16_t* w1b = (bf16_t*)(ws + 0);          // 160*608*2   = 194560
  bf16_t* w2b = (bf16_t*)(ws + 194560);     // 384*1376*2  = 1056768
  bf16_t* wdb = (bf16_t*)(ws + 1251328);    // 192*1440*2  = 552960
  bf16_t* w3b = (bf16_t*)(ws + 1804288);    // 640*160*2   = 204800
  float* bnc = (float*)(ws + 2009088);      // 1824*4      = 7296
  bf16_t* out1 = (bf16_t*)(ws + 2016384);   // 16384*152*2 = 4980736
  float* offs = (float*)(ws + 6997120);     // 16384*344*4 = 22544384
  bf16_t* a2 = (bf16_t*)(ws + 29541504);    // 16384*152*2 = 4980736  end 34522240
  float* out = (float*)d_out;

  prep_weights<<<3924, 256, 0, stream>>>(w1, w2, wd, w3, w1b, w2b, wdb, w3b);
  prep_bn<<<1, 640, 0, stream>>>(g1, b1, m1, v1, g2, b2, m2, v2, g3, b3, m3, v3, bnc);
  s1_conv1<<<512, 256, 0, stream>>>(x, w1b, bnc, out1);
  s2_offs<<<1024, 256, 0, stream>>>(out1, w2b, offs);
  s3_dconv<<<1024, 256, 0, stream>>>(out1, offs, wdb, bnc, a2);
  s4_conv3<<<1024, 256, 0, stream>>>(a2, w3b, bnc, x, out);
}